// Round 2
// 270.067 us; speedup vs baseline: 1.0338x; 1.0338x over previous
//
#include <hip/hip_runtime.h>

// Problem constants (B=8, N=8192, C=256, K=8, nblocks=8, blk=32)
#define NPTS 8192
#define CH   256
#define KNB  8
#define NROWS 65536        // B*N
#define ROWS_PER_BLK 32
#define ROWS_PER_IT  4
#define FT_STRIDE 36       // fT row stride: 16B-aligned, <=2-way bank alias (free)

#define NBLK_CONV 8192     // NROWS*CH/(256*8)
#define NBLK_S1   (NROWS / ROWS_PER_BLK)   // 2048
#define NBLK_S2   (NROWS / 16)             // 4096

typedef unsigned short ushort_t;
typedef float  f32x4  __attribute__((ext_vector_type(4)));   // native vec for nontemporal builtins

// XCD-aware swizzle: 8 batches == 8 XCDs. Hardware assigns block h -> XCD h%8
// (round-robin, m09/m157). Remap so XCD i exclusively owns batch i: its gather
// working set (4 MB bf16 slice) fits the XCD-private 4 MiB L2, and the
// conv->stage1->stage2 chain stays within one L2.
__device__ __forceinline__ int xcd_swz(int h, int cpx) {
    return (h & 7) * cpx + (h >> 3);     // bijective: grid % 8 == 0 everywhere
}

__device__ __forceinline__ ushort_t f32_to_bf16(float f) {
    unsigned int b = __float_as_uint(f);
    b += 0x7FFFu + ((b >> 16) & 1u);
    return (ushort_t)(b >> 16);
}
__device__ __forceinline__ float bf16_to_f32(ushort_t u) {
    return __uint_as_float(((unsigned int)u) << 16);
}
__device__ __forceinline__ unsigned int pack_bf16(float lo, float hi) {
    return (unsigned int)f32_to_bf16(lo) | ((unsigned int)f32_to_bf16(hi) << 16);
}

// ---------------------------------------------------------------------------
// Prepass: x fp32 -> bf16. Swizzled so batch i's xb slice is write-allocated
// into XCD i's L2 (stage1 gathers it from there). x read is pure streaming ->
// non-temporal so it doesn't displace the xb write lines.
// ---------------------------------------------------------------------------
__global__ __launch_bounds__(256) void pm_conv(
    const f32x4* __restrict__ x, uint4* __restrict__ xb)
{
    const int l = xcd_swz(blockIdx.x, NBLK_CONV / 8);
    const size_t i = (size_t)l * 256 + threadIdx.x;
    const f32x4 a = __builtin_nontemporal_load(&x[2 * i]);
    const f32x4 c = __builtin_nontemporal_load(&x[2 * i + 1]);
    uint4 o;
    o.x = pack_bf16(a.x, a.y);
    o.y = pack_bf16(a.z, a.w);
    o.z = pack_bf16(c.x, c.y);
    o.w = pack_bf16(c.z, c.w);
    xb[i] = o;
}

// ---------------------------------------------------------------------------
// Stage 1: s1 = rectify(x_bf16); t = monarch(s1) -> bf16.
// fT layout (transposed, stride-36) turns stage B's 32 ds_read_b32/thread
// into 8 ds_read_b128/thread (conflict-free).
// t store is non-temporal: t has zero reuse inside this kernel, and letting it
// write-allocate would evict the 9x-reused xb gather slice from L2.
// ---------------------------------------------------------------------------
__global__ __launch_bounds__(256) void pm_stage1(
    const ushort_t* __restrict__ xb, const float* __restrict__ dist,
    const int* __restrict__ idx, const float* __restrict__ w1,
    const float* __restrict__ w2, const float* __restrict__ bias,
    ushort_t* __restrict__ t)
{
    const int c = threadIdx.x;

    __shared__ float s1[ROWS_PER_IT][CH];
    __shared__ float fT[ROWS_PER_IT][8 * FT_STRIDE];

    // hoisted weights
    float4 w1r[8], w2r[8];
    {
        const float4* w1p = (const float4*)(w1 + c * 32);
        const float4* w2p = (const float4*)(w2 + ((c & 7) * 32 + (c >> 3)) * 32);
#pragma unroll
        for (int i = 0; i < 8; ++i) { w1r[i] = w1p[i]; w2r[i] = w2p[i]; }
    }
    const float bb = bias[c];
    const int l2   = c & 7;
    const int kb   = c >> 5;
    const int ftw  = l2 * FT_STRIDE + (c >> 3);   // stage A output slot

    const int rr   = __builtin_amdgcn_readfirstlane(threadIdx.x >> 6);
    const int lane = threadIdx.x & 63;

    const int lb       = xcd_swz(blockIdx.x, NBLK_S1 / 8);
    const int row_base = lb * ROWS_PER_BLK;
    const int b = row_base >> 13;                 // == blockIdx.x & 7 == XCD id
    const ushort4* x4 = (const ushort4*)(xb + (size_t)b * NPTS * CH);

    for (int it = 0; it < ROWS_PER_BLK / ROWS_PER_IT; ++it) {
        const int row  = row_base + it * ROWS_PER_IT + rr;   // wave-uniform
        const int rloc = row & (NPTS - 1);

        float d[KNB]; int nb[KNB];
#pragma unroll
        for (int k = 0; k < KNB; ++k) {
            d[k]  = dist[(size_t)row * KNB + k];
            nb[k] = idx[(size_t)row * KNB + k];
        }

        // issue all gathers (8B/lane = 512B/wave each) before consuming
        const ushort4 c0 = x4[(size_t)rloc * 64 + lane];
        ushort4 g[KNB];
#pragma unroll
        for (int k = 0; k < KNB; ++k) g[k] = x4[(size_t)nb[k] * 64 + lane];

        float mn = d[0];
#pragma unroll
        for (int k = 1; k < KNB; ++k) mn = fminf(mn, d[k]);
        float e[KNB]; float sum = 0.f;
#pragma unroll
        for (int k = 0; k < KNB; ++k) { e[k] = __expf(mn - d[k]); sum += e[k]; }
        const float inv = 0.05f / sum;

        float4 acc;
        acc.x = 0.95f * bf16_to_f32(c0.x);
        acc.y = 0.95f * bf16_to_f32(c0.y);
        acc.z = 0.95f * bf16_to_f32(c0.z);
        acc.w = 0.95f * bf16_to_f32(c0.w);
#pragma unroll
        for (int k = 0; k < KNB; ++k) {
            const float w = e[k] * inv;
            acc.x += w * bf16_to_f32(g[k].x);
            acc.y += w * bf16_to_f32(g[k].y);
            acc.z += w * bf16_to_f32(g[k].z);
            acc.w += w * bf16_to_f32(g[k].w);
        }
        ((float4*)&s1[rr][0])[lane] = acc;
        __syncthreads();

        // stage A: f[c] = sum_p w1[kb,q,p]*s1[kb*32+p]; write to fT transposed
#pragma unroll
        for (int r2 = 0; r2 < ROWS_PER_IT; ++r2) {
            const float4* sb = (const float4*)(&s1[r2][kb * 32]); // 2 addrs/wave: free
            float a = 0.f;
#pragma unroll
            for (int p4 = 0; p4 < 8; ++p4) {
                const float4 s = sb[p4];
                a += w1r[p4].x * s.x + w1r[p4].y * s.y
                   + w1r[p4].z * s.z + w1r[p4].w * s.w;
            }
            fT[r2][ftw] = a;    // <=2-way bank alias: free
        }
        __syncthreads();

        // stage B: t[c] = bias + sum_r w2[l2,s,r]*f[r*8+l2], f via fT b128 reads
#pragma unroll
        for (int r2 = 0; r2 < ROWS_PER_IT; ++r2) {
            const float4* fp = (const float4*)(&fT[r2][l2 * FT_STRIDE]); // 8 addrs: free
            float a = bb;
#pragma unroll
            for (int r4 = 0; r4 < 8; ++r4) {
                const float4 f = fp[r4];
                a += w2r[r4].x * f.x + w2r[r4].y * f.y
                   + w2r[r4].z * f.z + w2r[r4].w * f.w;
            }
            __builtin_nontemporal_store(
                f32_to_bf16(a),
                &t[(size_t)(row_base + it * ROWS_PER_IT + r2) * CH + c]);
        }
        __syncthreads();   // fT reads done before next iteration's blend/stage-A
    }
}

// ---------------------------------------------------------------------------
// Stage 2: out = 0.95*t + 0.05*sum_k w_k*t[b,idx_k] + rf  (t bf16)
// One wave per 4 rows; ALL 36 gathers + 4 rf loads issued before consumption.
// rf read / out write are pure streaming -> non-temporal, so the 9x-reused
// t gather slice stays resident in the XCD L2.
// ---------------------------------------------------------------------------
__global__ __launch_bounds__(256) void pm_stage2(
    const ushort_t* __restrict__ t, const float* __restrict__ dist,
    const int* __restrict__ idx, const float* __restrict__ rf,
    float* __restrict__ out)
{
    const int w     = __builtin_amdgcn_readfirstlane(threadIdx.x >> 6);
    const int lane  = threadIdx.x & 63;
    const int lb    = xcd_swz(blockIdx.x, NBLK_S2 / 8);
    const int wrow0 = lb * 16 + w * 4;
    const int b     = wrow0 >> 13;               // == blockIdx.x & 7 == XCD id
    const ushort4* tb = (const ushort4*)(t + (size_t)b * NPTS * CH);

    int   nb[4][KNB];
    float d [4][KNB];
#pragma unroll
    for (int r = 0; r < 4; ++r)
#pragma unroll
        for (int k = 0; k < KNB; ++k) {
            nb[r][k] = idx[(size_t)(wrow0 + r) * KNB + k];
            d [r][k] = dist[(size_t)(wrow0 + r) * KNB + k];
        }

    // issue everything
    ushort4 c0[4], g[4][KNB];
    f32x4   rv[4];
#pragma unroll
    for (int r = 0; r < 4; ++r) {
        const int rloc = (wrow0 + r) & (NPTS - 1);
        c0[r] = tb[(size_t)rloc * 64 + lane];
        rv[r] = __builtin_nontemporal_load(
                    &((const f32x4*)rf)[(size_t)(wrow0 + r) * 64 + lane]);
#pragma unroll
        for (int k = 0; k < KNB; ++k) g[r][k] = tb[(size_t)nb[r][k] * 64 + lane];
    }

#pragma unroll
    for (int r = 0; r < 4; ++r) {
        float mn = d[r][0];
#pragma unroll
        for (int k = 1; k < KNB; ++k) mn = fminf(mn, d[r][k]);
        float e[KNB]; float sum = 0.f;
#pragma unroll
        for (int k = 0; k < KNB; ++k) { e[k] = __expf(mn - d[r][k]); sum += e[k]; }
        const float inv = 0.05f / sum;

        f32x4 acc;
        acc.x = 0.95f * bf16_to_f32(c0[r].x) + rv[r].x;
        acc.y = 0.95f * bf16_to_f32(c0[r].y) + rv[r].y;
        acc.z = 0.95f * bf16_to_f32(c0[r].z) + rv[r].z;
        acc.w = 0.95f * bf16_to_f32(c0[r].w) + rv[r].w;
#pragma unroll
        for (int k = 0; k < KNB; ++k) {
            const float wk = e[k] * inv;
            acc.x += wk * bf16_to_f32(g[r][k].x);
            acc.y += wk * bf16_to_f32(g[r][k].y);
            acc.z += wk * bf16_to_f32(g[r][k].z);
            acc.w += wk * bf16_to_f32(g[r][k].w);
        }
        __builtin_nontemporal_store(
            acc, &((f32x4*)out)[(size_t)(wrow0 + r) * 64 + lane]);
    }
}

extern "C" void kernel_launch(void* const* d_in, const int* in_sizes, int n_in,
                              void* d_out, int out_size, void* d_ws, size_t ws_size,
                              hipStream_t stream) {
    const float* x    = (const float*)d_in[0];
    const float* dist = (const float*)d_in[1];
    const int*   idx  = (const int*)d_in[2];
    const float* rf   = (const float*)d_in[3];
    const float* w1   = (const float*)d_in[4];
    const float* w2   = (const float*)d_in[5];
    const float* bias = (const float*)d_in[6];
    float* out = (float*)d_out;

    ushort_t* t  = (ushort_t*)d_ws;                                   // 32 MiB bf16 t
    ushort_t* xb = (ushort_t*)((char*)d_ws + (size_t)NROWS * CH * 2); // 32 MiB bf16 x

    pm_conv  <<<NBLK_CONV, 256, 0, stream>>>((const f32x4*)x, (uint4*)xb);
    pm_stage1<<<NBLK_S1,   256, 0, stream>>>(xb, dist, idx, w1, w2, bias, t);
    pm_stage2<<<NBLK_S2,   256, 0, stream>>>(t, dist, idx, rf, out);
}

// Round 3
// 267.004 us; speedup vs baseline: 1.0457x; 1.0115x over previous
//
#include <hip/hip_runtime.h>

// Problem constants (B=8, N=8192, C=256, K=8, nblocks=8, blk=32)
#define NPTS 8192
#define CH   256
#define KNB  8
#define NROWS 65536        // B*N
#define ROWS_PER_BLK 32
#define ROWS_PER_IT  4
#define NIT (ROWS_PER_BLK / ROWS_PER_IT)   // 8
#define FT_STRIDE 36       // fT row stride: 16B-aligned, <=2-way bank alias (free)

#define NBLK_CONV 8192     // NROWS*CH/(256*8)
#define NBLK_S1   (NROWS / ROWS_PER_BLK)   // 2048
#define NBLK_S2   (NROWS / 16)             // 4096

typedef unsigned short ushort_t;
typedef float  f32x4  __attribute__((ext_vector_type(4)));   // native vec for nontemporal builtins

// Raw barrier: LDS ordering only (lgkmcnt drains ds ops); global loads stay
// in flight across it (hipcc's __syncthreads would emit vmcnt(0) and kill the
// gather pipeline). All cross-wave traffic here is LDS, so this is sufficient.
#define BARRIER_LDS() do { \
    asm volatile("s_waitcnt lgkmcnt(0)" ::: "memory"); \
    __builtin_amdgcn_s_barrier(); \
} while (0)

// XCD-aware swizzle: 8 batches == 8 XCDs. Block h -> XCD h%8 (round-robin),
// remap so XCD i exclusively owns batch i: gather working set (4 MB bf16
// slice) fits the XCD-private 4 MiB L2; conv->stage1->stage2 chains in-L2.
__device__ __forceinline__ int xcd_swz(int h, int cpx) {
    return (h & 7) * cpx + (h >> 3);     // bijective: grid % 8 == 0 everywhere
}

__device__ __forceinline__ ushort_t f32_to_bf16(float f) {
    unsigned int b = __float_as_uint(f);
    b += 0x7FFFu + ((b >> 16) & 1u);
    return (ushort_t)(b >> 16);
}
__device__ __forceinline__ float bf16_to_f32(ushort_t u) {
    return __uint_as_float(((unsigned int)u) << 16);
}
__device__ __forceinline__ unsigned int pack_bf16(float lo, float hi) {
    return (unsigned int)f32_to_bf16(lo) | ((unsigned int)f32_to_bf16(hi) << 16);
}

// ---------------------------------------------------------------------------
// Prepass: x fp32 -> bf16, XCD-pinned so batch i's xb slice lands in XCD i's L2.
// ---------------------------------------------------------------------------
__global__ __launch_bounds__(256) void pm_conv(
    const f32x4* __restrict__ x, uint4* __restrict__ xb)
{
    const int l = xcd_swz(blockIdx.x, NBLK_CONV / 8);
    const size_t i = (size_t)l * 256 + threadIdx.x;
    const f32x4 a = __builtin_nontemporal_load(&x[2 * i]);
    const f32x4 c = __builtin_nontemporal_load(&x[2 * i + 1]);
    uint4 o;
    o.x = pack_bf16(a.x, a.y);
    o.y = pack_bf16(a.z, a.w);
    o.z = pack_bf16(c.x, c.y);
    o.w = pack_bf16(c.z, c.w);
    xb[i] = o;
}

// ---------------------------------------------------------------------------
// Stage 1: s1 = rectify(x_bf16); t = monarch(s1) -> bf16.
// Software-pipelined: next row's dist/idx prefetched at loop top, next row's
// gathers issued after stage A (in flight across the LDS-only barriers and
// stage B, consumed by the next blend). Gather addresses are SGPR-based
// (readfirstlane'd wave-uniform idx) + lane*8 voffset: ~0 VALU per gather.
// 2 barriers/iter: post-blend (s1 ready) and post-stageA (fT ready); the WAR
// hazards of the next iteration are fenced by these same barriers.
// ---------------------------------------------------------------------------
__global__ __launch_bounds__(256, 4) void pm_stage1(
    const ushort_t* __restrict__ xb, const float* __restrict__ dist,
    const int* __restrict__ idx, const float* __restrict__ w1,
    const float* __restrict__ w2, const float* __restrict__ bias,
    ushort_t* __restrict__ t)
{
    const int c = threadIdx.x;

    __shared__ float s1[ROWS_PER_IT][CH];
    __shared__ float fT[ROWS_PER_IT][8 * FT_STRIDE];

    // hoisted weights (64 VGPRs; VGPR budget to 128 is free at 4 waves/SIMD)
    float4 w1r[8], w2r[8];
    {
        const float4* w1p = (const float4*)(w1 + c * 32);
        const float4* w2p = (const float4*)(w2 + ((c & 7) * 32 + (c >> 3)) * 32);
#pragma unroll
        for (int i = 0; i < 8; ++i) { w1r[i] = w1p[i]; w2r[i] = w2p[i]; }
    }
    const float bb = bias[c];
    const int l2   = c & 7;
    const int kb   = c >> 5;
    const int ftw  = l2 * FT_STRIDE + (c >> 3);   // stage A output slot

    const int rr   = __builtin_amdgcn_readfirstlane(threadIdx.x >> 6);
    const int lane = threadIdx.x & 63;

    const int lb       = xcd_swz(blockIdx.x, NBLK_S1 / 8);
    const int row_base = lb * ROWS_PER_BLK;
    const int b = row_base >> 13;                 // == blockIdx.x & 7 == XCD id
    const char* xbase  = (const char*)(xb + (size_t)b * NPTS * CH);
    const int laneoff  = lane * 8;                // 8 B per ushort4

    // ---- prologue: row(it=0) metadata + gathers ----
    float dcur[KNB]; int nbs[KNB];
    {
        const int row = row_base + rr;
        const float4 d0 = *(const float4*)(dist + (size_t)row * KNB);
        const float4 d1 = *(const float4*)(dist + (size_t)row * KNB + 4);
        const int4   i0 = *(const int4*)(idx + (size_t)row * KNB);
        const int4   i1 = *(const int4*)(idx + (size_t)row * KNB + 4);
        dcur[0]=d0.x; dcur[1]=d0.y; dcur[2]=d0.z; dcur[3]=d0.w;
        dcur[4]=d1.x; dcur[5]=d1.y; dcur[6]=d1.z; dcur[7]=d1.w;
        nbs[0]=__builtin_amdgcn_readfirstlane(i0.x);
        nbs[1]=__builtin_amdgcn_readfirstlane(i0.y);
        nbs[2]=__builtin_amdgcn_readfirstlane(i0.z);
        nbs[3]=__builtin_amdgcn_readfirstlane(i0.w);
        nbs[4]=__builtin_amdgcn_readfirstlane(i1.x);
        nbs[5]=__builtin_amdgcn_readfirstlane(i1.y);
        nbs[6]=__builtin_amdgcn_readfirstlane(i1.z);
        nbs[7]=__builtin_amdgcn_readfirstlane(i1.w);
    }
    ushort4 c0, g[KNB];
    {
        const int rloc = (row_base + rr) & (NPTS - 1);
        c0 = *(const ushort4*)(xbase + ((size_t)rloc << 9) + laneoff);
#pragma unroll
        for (int k = 0; k < KNB; ++k)
            g[k] = *(const ushort4*)(xbase + ((size_t)(unsigned)nbs[k] << 9) + laneoff);
    }

    for (int it = 0; it < NIT; ++it) {
        const bool more = (it + 1 < NIT);
        const int rown  = row_base + (more ? it + 1 : it) * ROWS_PER_IT + rr;

        // prefetch next row's metadata (in flight during blend + stage A)
        const float4 dn0 = *(const float4*)(dist + (size_t)rown * KNB);
        const float4 dn1 = *(const float4*)(dist + (size_t)rown * KNB + 4);
        const int4   in0 = *(const int4*)(idx + (size_t)rown * KNB);
        const int4   in1 = *(const int4*)(idx + (size_t)rown * KNB + 4);

        // ---- blend (consumes prefetched gathers) ----
        float mn = dcur[0];
#pragma unroll
        for (int k = 1; k < KNB; ++k) mn = fminf(mn, dcur[k]);
        float e[KNB]; float sum = 0.f;
#pragma unroll
        for (int k = 0; k < KNB; ++k) { e[k] = __expf(mn - dcur[k]); sum += e[k]; }
        const float inv = 0.05f / sum;

        float4 acc;
        acc.x = 0.95f * bf16_to_f32(c0.x);
        acc.y = 0.95f * bf16_to_f32(c0.y);
        acc.z = 0.95f * bf16_to_f32(c0.z);
        acc.w = 0.95f * bf16_to_f32(c0.w);
#pragma unroll
        for (int k = 0; k < KNB; ++k) {
            const float w = e[k] * inv;
            acc.x += w * bf16_to_f32(g[k].x);
            acc.y += w * bf16_to_f32(g[k].y);
            acc.z += w * bf16_to_f32(g[k].z);
            acc.w += w * bf16_to_f32(g[k].w);
        }
        ((float4*)&s1[rr][0])[lane] = acc;

        BARRIER_LDS();   // s1 ready; also fences stageB(it-1) fT reads vs stageA writes

        // ---- stage A: f[c] = sum_p w1[kb,q,p]*s1[kb*32+p] -> fT transposed ----
#pragma unroll
        for (int r2 = 0; r2 < ROWS_PER_IT; ++r2) {
            const float4* sb = (const float4*)(&s1[r2][kb * 32]); // 2 addrs/wave: free
            float a = 0.f;
#pragma unroll
            for (int p4 = 0; p4 < 8; ++p4) {
                const float4 s = sb[p4];
                a += w1r[p4].x * s.x + w1r[p4].y * s.y
                   + w1r[p4].z * s.z + w1r[p4].w * s.w;
            }
            fT[r2][ftw] = a;    // <=2-way bank alias: free
        }

        // ---- handoff + issue next row's gathers (fly across barrier+stageB) ----
        if (more) {
            dcur[0]=dn0.x; dcur[1]=dn0.y; dcur[2]=dn0.z; dcur[3]=dn0.w;
            dcur[4]=dn1.x; dcur[5]=dn1.y; dcur[6]=dn1.z; dcur[7]=dn1.w;
            nbs[0]=__builtin_amdgcn_readfirstlane(in0.x);
            nbs[1]=__builtin_amdgcn_readfirstlane(in0.y);
            nbs[2]=__builtin_amdgcn_readfirstlane(in0.z);
            nbs[3]=__builtin_amdgcn_readfirstlane(in0.w);
            nbs[4]=__builtin_amdgcn_readfirstlane(in1.x);
            nbs[5]=__builtin_amdgcn_readfirstlane(in1.y);
            nbs[6]=__builtin_amdgcn_readfirstlane(in1.z);
            nbs[7]=__builtin_amdgcn_readfirstlane(in1.w);
            const int rloc = rown & (NPTS - 1);
            c0 = *(const ushort4*)(xbase + ((size_t)rloc << 9) + laneoff);
#pragma unroll
            for (int k = 0; k < KNB; ++k)
                g[k] = *(const ushort4*)(xbase + ((size_t)(unsigned)nbs[k] << 9) + laneoff);
        }

        BARRIER_LDS();   // fT ready; also fences stageA s1 reads vs next blend writes

        // ---- stage B: t[c] = bias + sum_r w2[l2,s,r]*f[r*8+l2] ----
#pragma unroll
        for (int r2 = 0; r2 < ROWS_PER_IT; ++r2) {
            const float4* fp = (const float4*)(&fT[r2][l2 * FT_STRIDE]); // 8 addrs: free
            float a = bb;
#pragma unroll
            for (int r4 = 0; r4 < 8; ++r4) {
                const float4 f = fp[r4];
                a += w2r[r4].x * f.x + w2r[r4].y * f.y
                   + w2r[r4].z * f.z + w2r[r4].w * f.w;
            }
            __builtin_nontemporal_store(
                f32_to_bf16(a),
                &t[(size_t)(row_base + it * ROWS_PER_IT + r2) * CH + c]);
        }
        // no barrier here: next iteration's post-blend barrier fences fT WAR
    }
}

// ---------------------------------------------------------------------------
// Stage 2: out = 0.95*t + 0.05*sum_k w_k*t[b,idx_k] + rf  (t bf16)
// One wave per 4 rows; all 36 gathers + 4 rf loads issued before consumption.
// Gather addresses SGPR-based (readfirstlane'd idx). VGPR capped at 128.
// ---------------------------------------------------------------------------
__global__ __launch_bounds__(256, 4) void pm_stage2(
    const ushort_t* __restrict__ t, const float* __restrict__ dist,
    const int* __restrict__ idx, const float* __restrict__ rf,
    float* __restrict__ out)
{
    const int w     = __builtin_amdgcn_readfirstlane(threadIdx.x >> 6);
    const int lane  = threadIdx.x & 63;
    const int lb    = xcd_swz(blockIdx.x, NBLK_S2 / 8);
    const int wrow0 = lb * 16 + w * 4;
    const int b     = wrow0 >> 13;               // == blockIdx.x & 7 == XCD id
    const char* tbase = (const char*)(t + (size_t)b * NPTS * CH);
    const int laneoff = lane * 8;

    int   nbs[4][KNB];
    float d [4][KNB];
#pragma unroll
    for (int r = 0; r < 4; ++r) {
        const int row = wrow0 + r;
        const float4 d0 = *(const float4*)(dist + (size_t)row * KNB);
        const float4 d1 = *(const float4*)(dist + (size_t)row * KNB + 4);
        const int4   i0 = *(const int4*)(idx + (size_t)row * KNB);
        const int4   i1 = *(const int4*)(idx + (size_t)row * KNB + 4);
        d[r][0]=d0.x; d[r][1]=d0.y; d[r][2]=d0.z; d[r][3]=d0.w;
        d[r][4]=d1.x; d[r][5]=d1.y; d[r][6]=d1.z; d[r][7]=d1.w;
        nbs[r][0]=__builtin_amdgcn_readfirstlane(i0.x);
        nbs[r][1]=__builtin_amdgcn_readfirstlane(i0.y);
        nbs[r][2]=__builtin_amdgcn_readfirstlane(i0.z);
        nbs[r][3]=__builtin_amdgcn_readfirstlane(i0.w);
        nbs[r][4]=__builtin_amdgcn_readfirstlane(i1.x);
        nbs[r][5]=__builtin_amdgcn_readfirstlane(i1.y);
        nbs[r][6]=__builtin_amdgcn_readfirstlane(i1.z);
        nbs[r][7]=__builtin_amdgcn_readfirstlane(i1.w);
    }

    // issue everything
    ushort4 c0[4], g[4][KNB];
    f32x4   rv[4];
#pragma unroll
    for (int r = 0; r < 4; ++r) {
        const int rloc = (wrow0 + r) & (NPTS - 1);
        c0[r] = *(const ushort4*)(tbase + ((size_t)rloc << 9) + laneoff);
        rv[r] = __builtin_nontemporal_load(
                    &((const f32x4*)rf)[(size_t)(wrow0 + r) * 64 + lane]);
#pragma unroll
        for (int k = 0; k < KNB; ++k)
            g[r][k] = *(const ushort4*)(tbase + ((size_t)(unsigned)nbs[r][k] << 9) + laneoff);
    }

#pragma unroll
    for (int r = 0; r < 4; ++r) {
        float mn = d[r][0];
#pragma unroll
        for (int k = 1; k < KNB; ++k) mn = fminf(mn, d[r][k]);
        float e[KNB]; float sum = 0.f;
#pragma unroll
        for (int k = 0; k < KNB; ++k) { e[k] = __expf(mn - d[r][k]); sum += e[k]; }
        const float inv = 0.05f / sum;

        f32x4 acc;
        acc.x = 0.95f * bf16_to_f32(c0[r].x) + rv[r].x;
        acc.y = 0.95f * bf16_to_f32(c0[r].y) + rv[r].y;
        acc.z = 0.95f * bf16_to_f32(c0[r].z) + rv[r].z;
        acc.w = 0.95f * bf16_to_f32(c0[r].w) + rv[r].w;
#pragma unroll
        for (int k = 0; k < KNB; ++k) {
            const float wk = e[k] * inv;
            acc.x += wk * bf16_to_f32(g[r][k].x);
            acc.y += wk * bf16_to_f32(g[r][k].y);
            acc.z += wk * bf16_to_f32(g[r][k].z);
            acc.w += wk * bf16_to_f32(g[r][k].w);
        }
        __builtin_nontemporal_store(
            acc, &((f32x4*)out)[(size_t)(wrow0 + r) * 64 + lane]);
    }
}

extern "C" void kernel_launch(void* const* d_in, const int* in_sizes, int n_in,
                              void* d_out, int out_size, void* d_ws, size_t ws_size,
                              hipStream_t stream) {
    const float* x    = (const float*)d_in[0];
    const float* dist = (const float*)d_in[1];
    const int*   idx  = (const int*)d_in[2];
    const float* rf   = (const float*)d_in[3];
    const float* w1   = (const float*)d_in[4];
    const float* w2   = (const float*)d_in[5];
    const float* bias = (const float*)d_in[6];
    float* out = (float*)d_out;

    ushort_t* t  = (ushort_t*)d_ws;                                   // 32 MiB bf16 t
    ushort_t* xb = (ushort_t*)((char*)d_ws + (size_t)NROWS * CH * 2); // 32 MiB bf16 x

    pm_conv  <<<NBLK_CONV, 256, 0, stream>>>((const f32x4*)x, (uint4*)xb);
    pm_stage1<<<NBLK_S1,   256, 0, stream>>>(xb, dist, idx, w1, w2, bias, t);
    pm_stage2<<<NBLK_S2,   256, 0, stream>>>(t, dist, idx, rf, out);
}